// Round 21
// baseline (656.444 us; speedup 1.0000x reference)
//
#include <hip/hip_runtime.h>

#define B_    2
#define C_    64
#define D_    8
#define H_    56
#define W_    56
#define HW_   3136
#define DHW_  25088
#define G_    8
#define K_    27
#define OFFC_ 648

// padded activation layout: [b][g][dp=10][hp=58][wp=58][c8]
#define PD_   10
#define PH_   58
#define PW_   58
#define PSPAT (PD_ * PH_ * PW_)          // 33640 positions
#define PGSZ  (PSPAT * 8)                // elements per (b,g)

#define PACKB ((B_ * G_ * PSPAT + 255) / 256)   // 2103
#define TG1   ((OFFC_ * 2048) / 256)            // 5184
#define TG2   ((C_ * 1728) / 256)               // 432

typedef __attribute__((ext_vector_type(8))) short  bf16x8;
typedef __attribute__((ext_vector_type(4))) float  f32x4;
typedef __attribute__((ext_vector_type(8))) unsigned short ushort8;

__device__ __forceinline__ unsigned short f2bf(float f) {
    unsigned u = __float_as_uint(f);
    u = (u + 0x7FFFu + ((u >> 16) & 1u)) >> 16;
    return (unsigned short)u;
}
__device__ __forceinline__ float bf2f(unsigned short u) {
    return __uint_as_float(((unsigned)u) << 16);
}
__device__ __forceinline__ unsigned cvt_pk_bf16(float lo, float hi) {
    unsigned r;
    asm("v_cvt_pk_bf16_f32 %0, %1, %2" : "=v"(r) : "v"(lo), "v"(hi));
    return r;
}
// async global->LDS, 16B per lane; LDS dest must be lane-linear (base + lane*16)
__device__ __forceinline__ void gload_lds16(const void* g, void* l) {
    __builtin_amdgcn_global_load_lds(
        (const __attribute__((address_space(1))) unsigned int*)g,
        (__attribute__((address_space(3))) unsigned int*)l, 16, 0, 0);
}

// ---- fused prep: pack x (layer1 only) + conv-weight transpose + deform-weight transpose ----
__global__ __launch_bounds__(256) void prep_kernel(
    const float* __restrict__ x, unsigned short* __restrict__ xp, int npack,
    const float* __restrict__ woff, unsigned short* __restrict__ wT2,
    const float* __restrict__ wdc, unsigned short* __restrict__ wdcT)
{
    int blk = blockIdx.x;
    const int t = threadIdx.x;
    if (blk < npack) {
        int i = blk * 256 + t;
        if (i >= B_ * G_ * PSPAT) return;
        int b = i / (G_ * PSPAT);
        int rem = i - b * G_ * PSPAT;
        int g = rem / PSPAT, s = rem - g * PSPAT;
        int dp = s / (PH_ * PW_), r2 = s - dp * (PH_ * PW_);
        int hp = r2 / PW_, wp = r2 - hp * PW_;
        ushort8 v = {0, 0, 0, 0, 0, 0, 0, 0};
        if (dp >= 1 && dp <= D_ && hp >= 1 && hp <= H_ && wp >= 1 && wp <= W_) {
            const float* src = x + (size_t)(b * C_ + g * 8) * DHW_ + (dp - 1) * HW_ + (hp - 1) * W_ + (wp - 1);
            #pragma unroll
            for (int c = 0; c < 8; ++c) v[c] = f2bf(src[c * DHW_]);
        }
        *(ushort8*)(xp + (size_t)i * 8) = v;
        return;
    }
    blk -= npack;
    if (blk < TG1) {
        // wT2[oc][g][s][c8], s in [0,32): slot s holds tap = s ^ (oc&7) (0 if tap>=27)
        int i = blk * 256 + t;
        int oc = i >> 11, r = i & 2047;
        int g = r >> 8, r2 = r & 255;
        int s = r2 >> 3, c = r2 & 7;
        int tap = s ^ (oc & 7);
        unsigned short v = 0;
        if (tap < 27) v = f2bf(woff[(size_t)oc * 1728 + (g * 8 + c) * 27 + tap]);
        wT2[i] = v;
        return;
    }
    blk -= TG1;
    {
        // wdcT[oc][g*216 + tap*8 + c]
        int i = blk * 256 + t;
        int oc = i / 1728, k = i - oc * 1728;
        int icc = k / 216, r = k - icc * 216;
        int tap = r >> 3, icl = r & 7;
        wdcT[i] = f2bf(wdc[(size_t)oc * 1728 + (icc * 8 + icl) * 27 + tap]);
    }
}

#define CROW 512
__device__ __forceinline__ int swz(int row, int kByte) {
    return row * CROW + (kByte ^ ((row & 7) << 4));
}

// ---- offset conv implicit GEMM v11 (r20-proven): 8-wave double-buffered pipeline ----
// grid (11, 7, 16). block 512 = 8 waves, wave tile 64 oc x 64 pos.
#define XRH 12
#define XST 68       // slots per (dd,hl) row; 36 rows = 2448 slots used
#define XSLOT 2560   // 5 staging iters x 512
__global__ __launch_bounds__(512, 1) void conv_off_mfma_kernel(
    const unsigned short* __restrict__ xpad, const unsigned short* __restrict__ wT2,
    const float* __restrict__ bias, unsigned short* __restrict__ out)
{
    __shared__ __align__(16) unsigned short xr[2][XSLOT * 8];  // 2 x 40 KB
    __shared__ __align__(16) char wb[2][64 * CROW];            // 2 x 32 KB

    const int oc0  = blockIdx.x * 64;
    const int pos0 = blockIdx.y * 512;
    const int b    = blockIdx.z >> 3;
    const int d    = blockIdx.z & 7;
    const int h0   = pos0 / 56;
    const int t    = threadIdx.x;
    const int lane = t & 63;
    const int li   = lane & 15;
    const int ts   = lane >> 4;
    const int wv   = t >> 6;                 // 0..7, pos column

    int poff[4];
    #pragma unroll
    for (int pb = 0; pb < 4; ++pb) {
        int p  = pos0 + wv * 64 + pb * 16 + li;
        int pc = p < HW_ ? p : HW_ - 1;
        int hp = pc / 56, wp = pc - hp * 56;
        poff[pb] = (hp - h0) * XST + wp;
    }
    int offk[7];
    #pragma unroll
    for (int kk = 0; kk < 7; ++kk) {
        int tap = min(4 * kk + ts, 26);
        int dd = tap / 9, hh = (tap / 3) % 3, ww = tap - (tap / 3) * 3;
        offk[kk] = (dd * XRH + hh) * XST + ww;
    }

    // x staging: slot j = it*512+t -> (row=j/68, w=j%68); pad slots clamped, never read
    int xsrc[5];
    #pragma unroll
    for (int it = 0; it < 5; ++it) {
        int j = it * 512 + t;
        int row = j / XST, w = j - row * XST;
        int hl = row % XRH;
        int dd = min(row / XRH, 2);
        int dp = min(d + dd, PD_ - 1);
        int hp = min(h0 + hl, PH_ - 1);
        int wp = min(w, PW_ - 1);
        xsrc[it] = ((dp * PH_ + hp) * PW_ + wp) * 8;
    }
    // weight staging: linear both sides
    size_t wsrc[4];
    #pragma unroll
    for (int it = 0; it < 4; ++it) {
        int j = it * 512 + t;
        int rowg = min(oc0 + (j >> 5), OFFC_ - 1);
        wsrc[it] = ((size_t)rowg * 8) * 256 + (size_t)(j & 31) * 8;   // + g*256 later
    }

    f32x4 acc[4][4];
    #pragma unroll
    for (int i = 0; i < 4; ++i)
        #pragma unroll
        for (int j = 0; j < 4; ++j) acc[i][j] = (f32x4){0.f, 0.f, 0.f, 0.f};

    const unsigned short* xb0 = xpad + (size_t)(b * 8) * PGSZ;

    // prologue: stage g=0 into buffer 0
    #pragma unroll
    for (int it = 0; it < 5; ++it)
        gload_lds16(xb0 + xsrc[it], &xr[0][(it * 512 + t) * 8]);
    #pragma unroll
    for (int it = 0; it < 4; ++it)
        gload_lds16(wT2 + wsrc[it], wb[0] + (size_t)(it * 512 + t) * 16);
    __syncthreads();

    for (int g = 0; g < 8; ++g) {
        const int cur = g & 1;
        // issue next-g staging into the other buffer (flies under this g's MFMAs)
        if (g < 7) {
            const unsigned short* xb = xb0 + (size_t)(g + 1) * PGSZ;
            const unsigned short* wg = wT2 + (size_t)(g + 1) * 256;
            #pragma unroll
            for (int it = 0; it < 5; ++it)
                gload_lds16(xb + xsrc[it], &xr[cur ^ 1][(it * 512 + t) * 8]);
            #pragma unroll
            for (int it = 0; it < 4; ++it)
                gload_lds16(wg + wsrc[it], wb[cur ^ 1] + (size_t)(it * 512 + t) * 16);
        }
        // MFMA on buffer cur
        #pragma unroll
        for (int kk = 0; kk < 7; ++kk) {
            int tap = 4 * kk + ts;
            // K-tail (tap==27): wT2 stores exact zeros there, so A==0; B reads a
            // clamped in-bounds xr address.
            bf16x8 a[4];
            #pragma unroll
            for (int oa = 0; oa < 4; ++oa)
                a[oa] = *(const bf16x8*)(wb[cur] + swz(oa * 16 + li, tap * 16));
            #pragma unroll
            for (int pb = 0; pb < 4; ++pb) {
                bf16x8 bfrag = *(const bf16x8*)&xr[cur][(offk[kk] + poff[pb]) * 8];
                #pragma unroll
                for (int oa = 0; oa < 4; ++oa)
                    acc[oa][pb] = __builtin_amdgcn_mfma_f32_16x16x32_bf16(a[oa], bfrag, acc[oa][pb], 0, 0, 0);
            }
        }
        // drains vmcnt (next buffer staged during MFMAs) + retires reads of cur
        __syncthreads();
    }

    #pragma unroll
    for (int oa = 0; oa < 4; ++oa)
        #pragma unroll
        for (int pb = 0; pb < 4; ++pb)
            #pragma unroll
            for (int r = 0; r < 4; ++r) {
                int ocg = oc0 + oa * 16 + ts * 4 + r;
                int p   = pos0 + wv * 64 + pb * 16 + li;
                if (ocg < OFFC_ && p < HW_)
                    out[((size_t)(b * OFFC_ + ocg) * 8 + d) * HW_ + p] = f2bf(acc[oa][pb][r] + bias[ocg]);
            }
}

// ---- deformable conv v6: g-split 2 blocks, BRANCHLESS gather (live-mask K-tail) ----
#define REDS 17
__global__ __launch_bounds__(256, 4) void deform_mfma_kernel(
    const unsigned short* __restrict__ xpad, const unsigned short* __restrict__ off,
    const unsigned short* __restrict__ wT, float* __restrict__ hout,
    float* __restrict__ hpart)
{
    __shared__ float red[3 * 64 * REDS];  // 13 KB

    const int id   = blockIdx.y * 196 + blockIdx.x;    // 0..6271
    const int sid  = (id & 7) * 784 + (id >> 3);       // bijective (id>>3 < 784)
    const int pt   = sid % 196;
    const int rest = sid / 196;                        // 0..31
    const int bd   = rest >> 1;
    const int gs   = rest & 1;
    const int b    = bd >> 3;
    const int d    = bd & 7;
    const int pos0 = pt * 16;

    const int t    = threadIdx.x;
    const int lane = t & 63;
    const int li   = lane & 15, ts = lane >> 4;
    const int wv   = t >> 6;
    const int g    = gs * 4 + wv;

    const int p  = pos0 + li;
    const int hq = p / 56, wq = p - hq * 56;

    f32x4 acc[4];
    #pragma unroll
    for (int i = 0; i < 4; ++i) acc[i] = (f32x4){0.f, 0.f, 0.f, 0.f};

    {
        const unsigned short* xg = xpad + (size_t)(b * 8 + g) * PGSZ;
        const unsigned short* wg = wT + g * 216;
        #pragma unroll
        for (int kk = 0; kk < 7; ++kk) {
            int tap  = 4 * kk + ts;
            int tcl  = tap < 27 ? tap : 26;            // clamped tap (pad slice -> 26)
            float live = tap < 27 ? 1.f : 0.f;         // exact-zero mask for pad slice
            bf16x8 afr[4];
            #pragma unroll
            for (int oa = 0; oa < 4; ++oa)
                afr[oa] = *(const bf16x8*)(wg + (size_t)(oa * 16 + li) * 1728 + tcl * 8);
            bf16x8 bfr;
            {
                float a8[8] = {0.f, 0.f, 0.f, 0.f, 0.f, 0.f, 0.f, 0.f};
                int kd = tcl / 9 - 1, kh = (tcl / 3) % 3 - 1, kw = tcl - (tcl / 3) * 3 - 1;
                size_t ob = ((size_t)(b * OFFC_ + (g * 27 + tcl) * 3) * 8 + d) * HW_ + p;
                float pd = bf2f(off[ob])            + (float)(kd + d);
                float ph = bf2f(off[ob + DHW_])     + (float)(kh + hq);
                float pw = bf2f(off[ob + 2 * DHW_]) + (float)(kw + wq);
                float fd0 = floorf(pd), fh0 = floorf(ph), fw0 = floorf(pw);
                float fd = pd - fd0, fh = ph - fh0, fw = pw - fw0;
                int d0 = (int)fd0, h0i = (int)fh0, w0i = (int)fw0;
                #pragma unroll
                for (int tp = 0; tp < 8; ++tp) {
                    int dd = tp >> 2, hh = (tp >> 1) & 1, ww = tp & 1;
                    int di = d0 + dd, hi = h0i + hh, wi = w0i + ww;
                    float wgt = (dd ? fd : 1.f - fd) * (hh ? fh : 1.f - fh) * (ww ? fw : 1.f - fw);
                    bool valid = ((unsigned)di < 8u) && ((unsigned)hi < 56u) && ((unsigned)wi < 56u);
                    wgt = (valid ? wgt : 0.f) * live;
                    int dc = valid ? di : 0, hc = valid ? hi : 0, wc = valid ? wi : 0;
                    ushort8 v = *(const ushort8*)(xg + (((size_t)(dc + 1) * PH_ + hc + 1) * PW_ + wc + 1) * 8);
                    #pragma unroll
                    for (int c = 0; c < 8; ++c) a8[c] += bf2f(v[c]) * wgt;
                }
                union { unsigned u[4]; bf16x8 v; } cv;
                #pragma unroll
                for (int c = 0; c < 4; ++c) cv.u[c] = cvt_pk_bf16(a8[2 * c], a8[2 * c + 1]);
                bfr = cv.v;
            }
            #pragma unroll
            for (int oa = 0; oa < 4; ++oa)
                acc[oa] = __builtin_amdgcn_mfma_f32_16x16x32_bf16(afr[oa], bfr, acc[oa], 0, 0, 0);
        }
    }

    if (wv > 0) {
        float* rr = red + (wv - 1) * 64 * REDS + lane * REDS;
        #pragma unroll
        for (int oa = 0; oa < 4; ++oa)
            #pragma unroll
            for (int q = 0; q < 4; ++q)
                rr[oa * 4 + q] = acc[oa][q];
    }
    __syncthreads();
    if (wv == 0) {
        #pragma unroll
        for (int w2 = 0; w2 < 3; ++w2) {
            const float* rr = red + w2 * 64 * REDS + lane * REDS;
            #pragma unroll
            for (int oa = 0; oa < 4; ++oa)
                #pragma unroll
                for (int q = 0; q < 4; ++q)
                    acc[oa][q] += rr[oa * 4 + q];
        }
        float* dst = gs ? hpart : hout;
        #pragma unroll
        for (int oa = 0; oa < 4; ++oa)
            #pragma unroll
            for (int r = 0; r < 4; ++r) {
                int oc = oa * 16 + ts * 4 + r;
                dst[((size_t)(b * C_ + oc) * 8 + d) * HW_ + p] = acc[oa][r];
            }
    }
}

// ---- batchnorm stats (h = a + b), two-stage ----
__global__ __launch_bounds__(256) void bn_stats_partial_kernel(
    const float* __restrict__ ha, const float* __restrict__ hb, float* __restrict__ part)
{
    const int c = blockIdx.x, s = blockIdx.y;
    const int t = threadIdx.x;
    const int SL = (B_ * DHW_) / 16;
    float sum = 0.f, sq = 0.f;
    for (int j = s * SL + t * 4; j < (s + 1) * SL; j += 1024) {
        int b = j / DHW_, i = j - b * DHW_;
        size_t base = (size_t)(b * C_ + c) * DHW_ + i;
        f32x4 va = *(const f32x4*)(ha + base);
        f32x4 vb = *(const f32x4*)(hb + base);
        #pragma unroll
        for (int q = 0; q < 4; ++q) { float v = va[q] + vb[q]; sum += v; sq += v * v; }
    }
    #pragma unroll
    for (int o = 32; o > 0; o >>= 1) {
        sum += __shfl_down(sum, o);
        sq  += __shfl_down(sq, o);
    }
    __shared__ float rs[4], rq[4];
    if ((t & 63) == 0) { rs[t >> 6] = sum; rq[t >> 6] = sq; }
    __syncthreads();
    if (t == 0) {
        part[c * 16 + s]        = rs[0] + rs[1] + rs[2] + rs[3];
        part[1024 + c * 16 + s] = rq[0] + rq[1] + rq[2] + rq[3];
    }
}

__global__ void bn_stats_finalize_kernel(
    const float* __restrict__ part, float* __restrict__ stats)
{
    int c = threadIdx.x;
    if (c >= 64) return;
    float s = 0.f, q = 0.f;
    for (int i = 0; i < 16; ++i) { s += part[c * 16 + i]; q += part[1024 + c * 16 + i]; }
    float inv = 1.f / (float)(B_ * DHW_);
    float m   = s * inv;
    float var = q * inv - m * m;
    stats[c]      = m;
    stats[C_ + c] = rsqrtf(fmaxf(var, 0.f) + 1e-5f);
}

// ---- bn + relu + pack to padded bf16 (h = a + b) ----
__global__ __launch_bounds__(256) void bn_relu_pack_kernel(
    const float* __restrict__ ha, const float* __restrict__ hb,
    const float* __restrict__ stats,
    const float* __restrict__ gamma, const float* __restrict__ beta,
    unsigned short* __restrict__ out)
{
    int i = blockIdx.x * 256 + threadIdx.x;          // over B*G*PSPAT
    if (i >= B_ * G_ * PSPAT) return;
    int b = i / (G_ * PSPAT);
    int rem = i - b * G_ * PSPAT;
    int g = rem / PSPAT, s = rem - g * PSPAT;
    int dp = s / (PH_ * PW_), r2 = s - dp * (PH_ * PW_);
    int hp = r2 / PW_, wp = r2 - hp * PW_;
    ushort8 o8 = {0, 0, 0, 0, 0, 0, 0, 0};
    if (dp >= 1 && dp <= D_ && hp >= 1 && hp <= H_ && wp >= 1 && wp <= W_) {
        int dhw = (dp - 1) * HW_ + (hp - 1) * W_ + (wp - 1);
        #pragma unroll
        for (int c = 0; c < 8; ++c) {
            int ch = g * 8 + c;
            size_t base = (size_t)(b * C_ + ch) * DHW_ + dhw;
            float v = (ha[base] + hb[base] - stats[ch]) * stats[C_ + ch] * gamma[ch] + beta[ch];
            o8[c] = f2bf(v > 0.f ? v : 0.f);
        }
    }
    *(ushort8*)(out + (size_t)i * 8) = o8;
}

// ---- bn + residual + relu (reads hbuf+hpart, writes hbuf in place) ----
__global__ __launch_bounds__(256) void bn_add_relu_kernel(
    float* __restrict__ hbuf, const float* __restrict__ hpart,
    const float* __restrict__ xres, const float* __restrict__ stats,
    const float* __restrict__ gamma, const float* __restrict__ beta)
{
    const int n = B_ * C_ * DHW_;
    for (int i = blockIdx.x * 256 + threadIdx.x; i < n; i += gridDim.x * 256) {
        int c = (i / DHW_) & (C_ - 1);
        float v = (hbuf[i] + hpart[i] - stats[c]) * stats[C_ + c] * gamma[c] + beta[c] + xres[i];
        hbuf[i] = v > 0.f ? v : 0.f;
    }
}

extern "C" void kernel_launch(void* const* d_in, const int* in_sizes, int n_in,
                              void* d_out, int out_size, void* d_ws, size_t ws_size,
                              hipStream_t stream)
{
    const float* x      = (const float*)d_in[0];
    const float* w_off1 = (const float*)d_in[1];
    const float* b_off1 = (const float*)d_in[2];
    const float* w_dc1  = (const float*)d_in[3];
    const float* gamma1 = (const float*)d_in[4];
    const float* beta1  = (const float*)d_in[5];
    const float* w_off2 = (const float*)d_in[6];
    const float* b_off2 = (const float*)d_in[7];
    const float* w_dc2  = (const float*)d_in[8];
    const float* gamma2 = (const float*)d_in[9];
    const float* beta2  = (const float*)d_in[10];
    float* out = (float*)d_out;

    unsigned short* offb = (unsigned short*)d_ws;                    // 32,514,048
    unsigned short* xpad = offb + (size_t)B_ * OFFC_ * DHW_;         //  4,305,920
    unsigned short* h1pd = xpad + (size_t)B_ * G_ * PGSZ;            //  4,305,920
    unsigned short* wT2  = h1pd + (size_t)B_ * G_ * PGSZ;            //  1,327,104
    unsigned short* wdcT = wT2  + (size_t)OFFC_ * 2048;              //    110,592
    float* h1raw = (float*)(wdcT + (size_t)C_ * 1728);               //  3,211,264 f32
    float* hpart = h1raw + (size_t)B_ * C_ * DHW_;                   //  3,211,264 f32
    float* stats = hpart + (size_t)B_ * C_ * DHW_;                   //  128 f32
    float* part  = stats + 128;                                      //  2048 f32

    dim3 cgrid(11, 7, B_ * D_);
    dim3 dgrid(196, 32);
    dim3 sgrid(C_, 16);

    prep_kernel             <<<PACKB + TG1 + TG2, 256, 0, stream>>>(x, xpad, PACKB, w_off1, wT2, w_dc1, wdcT);
    conv_off_mfma_kernel    <<<cgrid, 512, 0, stream>>>(xpad, wT2, b_off1, offb);
    deform_mfma_kernel      <<<dgrid, 256, 0, stream>>>(xpad, offb, wdcT, h1raw, hpart);
    bn_stats_partial_kernel <<<sgrid, 256, 0, stream>>>(h1raw, hpart, part);
    bn_stats_finalize_kernel<<<1, 64, 0, stream>>>(part, stats);
    bn_relu_pack_kernel     <<<PACKB, 256, 0, stream>>>(h1raw, hpart, stats, gamma1, beta1, h1pd);

    prep_kernel             <<<TG1 + TG2, 256, 0, stream>>>(nullptr, nullptr, 0, w_off2, wT2, w_dc2, wdcT);
    conv_off_mfma_kernel    <<<cgrid, 512, 0, stream>>>(h1pd, wT2, b_off2, offb);
    deform_mfma_kernel      <<<dgrid, 256, 0, stream>>>(h1pd, offb, wdcT, out, hpart);
    bn_stats_partial_kernel <<<sgrid, 256, 0, stream>>>(out, hpart, part);
    bn_stats_finalize_kernel<<<1, 64, 0, stream>>>(part, stats);
    bn_add_relu_kernel      <<<1024, 256, 0, stream>>>(out, hpart, x, stats, gamma2, beta2);
}

// Round 22
// 639.479 us; speedup vs baseline: 1.0265x; 1.0265x over previous
//
#include <hip/hip_runtime.h>

#define B_    2
#define C_    64
#define D_    8
#define H_    56
#define W_    56
#define HW_   3136
#define DHW_  25088
#define G_    8
#define K_    27
#define OFFC_ 648

// padded activation layout: [b][g][dp=10][hp=58][wp=58][c8]
#define PD_   10
#define PH_   58
#define PW_   58
#define PSPAT (PD_ * PH_ * PW_)          // 33640 positions
#define PGSZ  (PSPAT * 8)                // elements per (b,g)

#define PACKB ((B_ * G_ * PSPAT + 255) / 256)   // 2103
#define TG1   ((OFFC_ * 2048) / 256)            // 5184
#define TG2   ((C_ * 1728) / 256)               // 432

typedef __attribute__((ext_vector_type(8))) short  bf16x8;
typedef __attribute__((ext_vector_type(4))) float  f32x4;
typedef __attribute__((ext_vector_type(8))) unsigned short ushort8;

__device__ __forceinline__ unsigned short f2bf(float f) {
    unsigned u = __float_as_uint(f);
    u = (u + 0x7FFFu + ((u >> 16) & 1u)) >> 16;
    return (unsigned short)u;
}
__device__ __forceinline__ float bf2f(unsigned short u) {
    return __uint_as_float(((unsigned)u) << 16);
}
__device__ __forceinline__ unsigned cvt_pk_bf16(float lo, float hi) {
    unsigned r;
    asm("v_cvt_pk_bf16_f32 %0, %1, %2" : "=v"(r) : "v"(lo), "v"(hi));
    return r;
}
// async global->LDS, 16B per lane; LDS dest must be lane-linear (base + lane*16)
__device__ __forceinline__ void gload_lds16(const void* g, void* l) {
    __builtin_amdgcn_global_load_lds(
        (const __attribute__((address_space(1))) unsigned int*)g,
        (__attribute__((address_space(3))) unsigned int*)l, 16, 0, 0);
}

// ---- fused prep: pack x (layer1 only) + conv-weight transpose + deform-weight transpose ----
__global__ __launch_bounds__(256) void prep_kernel(
    const float* __restrict__ x, unsigned short* __restrict__ xp, int npack,
    const float* __restrict__ woff, unsigned short* __restrict__ wT2,
    const float* __restrict__ wdc, unsigned short* __restrict__ wdcT)
{
    int blk = blockIdx.x;
    const int t = threadIdx.x;
    if (blk < npack) {
        int i = blk * 256 + t;
        if (i >= B_ * G_ * PSPAT) return;
        int b = i / (G_ * PSPAT);
        int rem = i - b * G_ * PSPAT;
        int g = rem / PSPAT, s = rem - g * PSPAT;
        int dp = s / (PH_ * PW_), r2 = s - dp * (PH_ * PW_);
        int hp = r2 / PW_, wp = r2 - hp * PW_;
        ushort8 v = {0, 0, 0, 0, 0, 0, 0, 0};
        if (dp >= 1 && dp <= D_ && hp >= 1 && hp <= H_ && wp >= 1 && wp <= W_) {
            const float* src = x + (size_t)(b * C_ + g * 8) * DHW_ + (dp - 1) * HW_ + (hp - 1) * W_ + (wp - 1);
            #pragma unroll
            for (int c = 0; c < 8; ++c) v[c] = f2bf(src[c * DHW_]);
        }
        *(ushort8*)(xp + (size_t)i * 8) = v;
        return;
    }
    blk -= npack;
    if (blk < TG1) {
        // wT2[oc][g][s][c8], s in [0,32): slot s holds tap = s ^ (oc&7) (0 if tap>=27)
        int i = blk * 256 + t;
        int oc = i >> 11, r = i & 2047;
        int g = r >> 8, r2 = r & 255;
        int s = r2 >> 3, c = r2 & 7;
        int tap = s ^ (oc & 7);
        unsigned short v = 0;
        if (tap < 27) v = f2bf(woff[(size_t)oc * 1728 + (g * 8 + c) * 27 + tap]);
        wT2[i] = v;
        return;
    }
    blk -= TG1;
    {
        // wdcT[oc][g*216 + tap*8 + c]
        int i = blk * 256 + t;
        int oc = i / 1728, k = i - oc * 1728;
        int icc = k / 216, r = k - icc * 216;
        int tap = r >> 3, icl = r & 7;
        wdcT[i] = f2bf(wdc[(size_t)oc * 1728 + (icc * 8 + icl) * 27 + tap]);
    }
}

#define CROW 512
__device__ __forceinline__ int swz(int row, int kByte) {
    return row * CROW + (kByte ^ ((row & 7) << 4));
}

// ---- offset conv implicit GEMM v11 (r20-proven): 8-wave double-buffered pipeline ----
// grid (11, 7, 16). block 512 = 8 waves, wave tile 64 oc x 64 pos.
#define XRH 12
#define XST 68       // slots per (dd,hl) row; 36 rows = 2448 slots used
#define XSLOT 2560   // 5 staging iters x 512
__global__ __launch_bounds__(512, 1) void conv_off_mfma_kernel(
    const unsigned short* __restrict__ xpad, const unsigned short* __restrict__ wT2,
    const float* __restrict__ bias, unsigned short* __restrict__ out)
{
    __shared__ __align__(16) unsigned short xr[2][XSLOT * 8];  // 2 x 40 KB
    __shared__ __align__(16) char wb[2][64 * CROW];            // 2 x 32 KB

    const int oc0  = blockIdx.x * 64;
    const int pos0 = blockIdx.y * 512;
    const int b    = blockIdx.z >> 3;
    const int d    = blockIdx.z & 7;
    const int h0   = pos0 / 56;
    const int t    = threadIdx.x;
    const int lane = t & 63;
    const int li   = lane & 15;
    const int ts   = lane >> 4;
    const int wv   = t >> 6;                 // 0..7, pos column

    int poff[4];
    #pragma unroll
    for (int pb = 0; pb < 4; ++pb) {
        int p  = pos0 + wv * 64 + pb * 16 + li;
        int pc = p < HW_ ? p : HW_ - 1;
        int hp = pc / 56, wp = pc - hp * 56;
        poff[pb] = (hp - h0) * XST + wp;
    }
    int offk[7];
    #pragma unroll
    for (int kk = 0; kk < 7; ++kk) {
        int tap = min(4 * kk + ts, 26);
        int dd = tap / 9, hh = (tap / 3) % 3, ww = tap - (tap / 3) * 3;
        offk[kk] = (dd * XRH + hh) * XST + ww;
    }

    // x staging: slot j = it*512+t -> (row=j/68, w=j%68); pad slots clamped, never read
    int xsrc[5];
    #pragma unroll
    for (int it = 0; it < 5; ++it) {
        int j = it * 512 + t;
        int row = j / XST, w = j - row * XST;
        int hl = row % XRH;
        int dd = min(row / XRH, 2);
        int dp = min(d + dd, PD_ - 1);
        int hp = min(h0 + hl, PH_ - 1);
        int wp = min(w, PW_ - 1);
        xsrc[it] = ((dp * PH_ + hp) * PW_ + wp) * 8;
    }
    // weight staging: linear both sides
    size_t wsrc[4];
    #pragma unroll
    for (int it = 0; it < 4; ++it) {
        int j = it * 512 + t;
        int rowg = min(oc0 + (j >> 5), OFFC_ - 1);
        wsrc[it] = ((size_t)rowg * 8) * 256 + (size_t)(j & 31) * 8;   // + g*256 later
    }

    f32x4 acc[4][4];
    #pragma unroll
    for (int i = 0; i < 4; ++i)
        #pragma unroll
        for (int j = 0; j < 4; ++j) acc[i][j] = (f32x4){0.f, 0.f, 0.f, 0.f};

    const unsigned short* xb0 = xpad + (size_t)(b * 8) * PGSZ;

    // prologue: stage g=0 into buffer 0
    #pragma unroll
    for (int it = 0; it < 5; ++it)
        gload_lds16(xb0 + xsrc[it], &xr[0][(it * 512 + t) * 8]);
    #pragma unroll
    for (int it = 0; it < 4; ++it)
        gload_lds16(wT2 + wsrc[it], wb[0] + (size_t)(it * 512 + t) * 16);
    __syncthreads();

    for (int g = 0; g < 8; ++g) {
        const int cur = g & 1;
        // issue next-g staging into the other buffer (flies under this g's MFMAs)
        if (g < 7) {
            const unsigned short* xb = xb0 + (size_t)(g + 1) * PGSZ;
            const unsigned short* wg = wT2 + (size_t)(g + 1) * 256;
            #pragma unroll
            for (int it = 0; it < 5; ++it)
                gload_lds16(xb + xsrc[it], &xr[cur ^ 1][(it * 512 + t) * 8]);
            #pragma unroll
            for (int it = 0; it < 4; ++it)
                gload_lds16(wg + wsrc[it], wb[cur ^ 1] + (size_t)(it * 512 + t) * 16);
        }
        // MFMA on buffer cur
        #pragma unroll
        for (int kk = 0; kk < 7; ++kk) {
            int tap = 4 * kk + ts;
            // K-tail (tap==27): wT2 stores exact zeros there, so A==0; B reads a
            // clamped in-bounds xr address.
            bf16x8 a[4];
            #pragma unroll
            for (int oa = 0; oa < 4; ++oa)
                a[oa] = *(const bf16x8*)(wb[cur] + swz(oa * 16 + li, tap * 16));
            #pragma unroll
            for (int pb = 0; pb < 4; ++pb) {
                bf16x8 bfrag = *(const bf16x8*)&xr[cur][(offk[kk] + poff[pb]) * 8];
                #pragma unroll
                for (int oa = 0; oa < 4; ++oa)
                    acc[oa][pb] = __builtin_amdgcn_mfma_f32_16x16x32_bf16(a[oa], bfrag, acc[oa][pb], 0, 0, 0);
            }
        }
        // drains vmcnt (next buffer staged during MFMAs) + retires reads of cur
        __syncthreads();
    }

    #pragma unroll
    for (int oa = 0; oa < 4; ++oa)
        #pragma unroll
        for (int pb = 0; pb < 4; ++pb)
            #pragma unroll
            for (int r = 0; r < 4; ++r) {
                int ocg = oc0 + oa * 16 + ts * 4 + r;
                int p   = pos0 + wv * 64 + pb * 16 + li;
                if (ocg < OFFC_ && p < HW_)
                    out[((size_t)(b * OFFC_ + ocg) * 8 + d) * HW_ + p] = f2bf(acc[oa][pb][r] + bias[ocg]);
            }
}

// ---- deformable conv v5 (r18/r20-proven): g-split across 2 blocks, 4 waves x 1 group ----
#define REDS 17
__global__ __launch_bounds__(256, 4) void deform_mfma_kernel(
    const unsigned short* __restrict__ xpad, const unsigned short* __restrict__ off,
    const unsigned short* __restrict__ wT, float* __restrict__ hout,
    float* __restrict__ hpart)
{
    __shared__ float red[3 * 64 * REDS];  // 13 KB

    const int id   = blockIdx.y * 196 + blockIdx.x;    // 0..6271
    const int sid  = (id & 7) * 784 + (id >> 3);       // bijective (id>>3 < 784)
    const int pt   = sid % 196;
    const int rest = sid / 196;                        // 0..31
    const int bd   = rest >> 1;
    const int gs   = rest & 1;
    const int b    = bd >> 3;
    const int d    = bd & 7;
    const int pos0 = pt * 16;

    const int t    = threadIdx.x;
    const int lane = t & 63;
    const int li   = lane & 15, ts = lane >> 4;
    const int wv   = t >> 6;
    const int g    = gs * 4 + wv;

    const int p  = pos0 + li;
    const int hq = p / 56, wq = p - hq * 56;

    f32x4 acc[4];
    #pragma unroll
    for (int i = 0; i < 4; ++i) acc[i] = (f32x4){0.f, 0.f, 0.f, 0.f};

    {
        const unsigned short* xg = xpad + (size_t)(b * 8 + g) * PGSZ;
        const unsigned short* wg = wT + g * 216;
        #pragma unroll
        for (int kk = 0; kk < 7; ++kk) {
            int tap = 4 * kk + ts;
            int tc  = tap < 27 ? tap : 26;
            bf16x8 afr[4];
            #pragma unroll
            for (int oa = 0; oa < 4; ++oa)
                afr[oa] = *(const bf16x8*)(wg + (size_t)(oa * 16 + li) * 1728 + tc * 8);
            bf16x8 bfr;
            {
                float a8[8] = {0.f, 0.f, 0.f, 0.f, 0.f, 0.f, 0.f, 0.f};
                if (tap < 27) {
                    int kd = tap / 9 - 1, kh = (tap / 3) % 3 - 1, kw = tap - (tap / 3) * 3 - 1;
                    size_t ob = ((size_t)(b * OFFC_ + (g * 27 + tap) * 3) * 8 + d) * HW_ + p;
                    float pd = bf2f(off[ob])            + (float)(kd + d);
                    float ph = bf2f(off[ob + DHW_])     + (float)(kh + hq);
                    float pw = bf2f(off[ob + 2 * DHW_]) + (float)(kw + wq);
                    float fd0 = floorf(pd), fh0 = floorf(ph), fw0 = floorf(pw);
                    float fd = pd - fd0, fh = ph - fh0, fw = pw - fw0;
                    int d0 = (int)fd0, h0i = (int)fh0, w0i = (int)fw0;
                    #pragma unroll
                    for (int tp = 0; tp < 8; ++tp) {
                        int dd = tp >> 2, hh = (tp >> 1) & 1, ww = tp & 1;
                        int di = d0 + dd, hi = h0i + hh, wi = w0i + ww;
                        float wgt = (dd ? fd : 1.f - fd) * (hh ? fh : 1.f - fh) * (ww ? fw : 1.f - fw);
                        bool valid = ((unsigned)di < 8u) && ((unsigned)hi < 56u) && ((unsigned)wi < 56u);
                        wgt = valid ? wgt : 0.f;
                        int dc = valid ? di : 0, hc = valid ? hi : 0, wc = valid ? wi : 0;
                        ushort8 v = *(const ushort8*)(xg + (((size_t)(dc + 1) * PH_ + hc + 1) * PW_ + wc + 1) * 8);
                        #pragma unroll
                        for (int c = 0; c < 8; ++c) a8[c] += bf2f(v[c]) * wgt;
                    }
                }
                union { unsigned u[4]; bf16x8 v; } cv;
                #pragma unroll
                for (int c = 0; c < 4; ++c) cv.u[c] = cvt_pk_bf16(a8[2 * c], a8[2 * c + 1]);
                bfr = cv.v;
            }
            #pragma unroll
            for (int oa = 0; oa < 4; ++oa)
                acc[oa] = __builtin_amdgcn_mfma_f32_16x16x32_bf16(afr[oa], bfr, acc[oa], 0, 0, 0);
        }
    }

    if (wv > 0) {
        float* rr = red + (wv - 1) * 64 * REDS + lane * REDS;
        #pragma unroll
        for (int oa = 0; oa < 4; ++oa)
            #pragma unroll
            for (int q = 0; q < 4; ++q)
                rr[oa * 4 + q] = acc[oa][q];
    }
    __syncthreads();
    if (wv == 0) {
        #pragma unroll
        for (int w2 = 0; w2 < 3; ++w2) {
            const float* rr = red + w2 * 64 * REDS + lane * REDS;
            #pragma unroll
            for (int oa = 0; oa < 4; ++oa)
                #pragma unroll
                for (int q = 0; q < 4; ++q)
                    acc[oa][q] += rr[oa * 4 + q];
        }
        float* dst = gs ? hpart : hout;
        #pragma unroll
        for (int oa = 0; oa < 4; ++oa)
            #pragma unroll
            for (int r = 0; r < 4; ++r) {
                int oc = oa * 16 + ts * 4 + r;
                dst[((size_t)(b * C_ + oc) * 8 + d) * HW_ + p] = acc[oa][r];
            }
    }
}

// ---- batchnorm stats (h = a + b), two-stage ----
__global__ __launch_bounds__(256) void bn_stats_partial_kernel(
    const float* __restrict__ ha, const float* __restrict__ hb, float* __restrict__ part)
{
    const int c = blockIdx.x, s = blockIdx.y;
    const int t = threadIdx.x;
    const int SL = (B_ * DHW_) / 16;
    float sum = 0.f, sq = 0.f;
    for (int j = s * SL + t * 4; j < (s + 1) * SL; j += 1024) {
        int b = j / DHW_, i = j - b * DHW_;
        size_t base = (size_t)(b * C_ + c) * DHW_ + i;
        f32x4 va = *(const f32x4*)(ha + base);
        f32x4 vb = *(const f32x4*)(hb + base);
        #pragma unroll
        for (int q = 0; q < 4; ++q) { float v = va[q] + vb[q]; sum += v; sq += v * v; }
    }
    #pragma unroll
    for (int o = 32; o > 0; o >>= 1) {
        sum += __shfl_down(sum, o);
        sq  += __shfl_down(sq, o);
    }
    __shared__ float rs[4], rq[4];
    if ((t & 63) == 0) { rs[t >> 6] = sum; rq[t >> 6] = sq; }
    __syncthreads();
    if (t == 0) {
        part[c * 16 + s]        = rs[0] + rs[1] + rs[2] + rs[3];
        part[1024 + c * 16 + s] = rq[0] + rq[1] + rq[2] + rq[3];
    }
}

__global__ void bn_stats_finalize_kernel(
    const float* __restrict__ part, float* __restrict__ stats)
{
    int c = threadIdx.x;
    if (c >= 64) return;
    float s = 0.f, q = 0.f;
    for (int i = 0; i < 16; ++i) { s += part[c * 16 + i]; q += part[1024 + c * 16 + i]; }
    float inv = 1.f / (float)(B_ * DHW_);
    float m   = s * inv;
    float var = q * inv - m * m;
    stats[c]      = m;
    stats[C_ + c] = rsqrtf(fmaxf(var, 0.f) + 1e-5f);
}

// ---- bn + relu + pack to padded bf16 (h = a + b) ----
__global__ __launch_bounds__(256) void bn_relu_pack_kernel(
    const float* __restrict__ ha, const float* __restrict__ hb,
    const float* __restrict__ stats,
    const float* __restrict__ gamma, const float* __restrict__ beta,
    unsigned short* __restrict__ out)
{
    int i = blockIdx.x * 256 + threadIdx.x;          // over B*G*PSPAT
    if (i >= B_ * G_ * PSPAT) return;
    int b = i / (G_ * PSPAT);
    int rem = i - b * G_ * PSPAT;
    int g = rem / PSPAT, s = rem - g * PSPAT;
    int dp = s / (PH_ * PW_), r2 = s - dp * (PH_ * PW_);
    int hp = r2 / PW_, wp = r2 - hp * PW_;
    ushort8 o8 = {0, 0, 0, 0, 0, 0, 0, 0};
    if (dp >= 1 && dp <= D_ && hp >= 1 && hp <= H_ && wp >= 1 && wp <= W_) {
        int dhw = (dp - 1) * HW_ + (hp - 1) * W_ + (wp - 1);
        #pragma unroll
        for (int c = 0; c < 8; ++c) {
            int ch = g * 8 + c;
            size_t base = (size_t)(b * C_ + ch) * DHW_ + dhw;
            float v = (ha[base] + hb[base] - stats[ch]) * stats[C_ + ch] * gamma[ch] + beta[ch];
            o8[c] = f2bf(v > 0.f ? v : 0.f);
        }
    }
    *(ushort8*)(out + (size_t)i * 8) = o8;
}

// ---- bn + residual + relu (reads hbuf+hpart, writes hbuf in place) ----
__global__ __launch_bounds__(256) void bn_add_relu_kernel(
    float* __restrict__ hbuf, const float* __restrict__ hpart,
    const float* __restrict__ xres, const float* __restrict__ stats,
    const float* __restrict__ gamma, const float* __restrict__ beta)
{
    const int n = B_ * C_ * DHW_;
    for (int i = blockIdx.x * 256 + threadIdx.x; i < n; i += gridDim.x * 256) {
        int c = (i / DHW_) & (C_ - 1);
        float v = (hbuf[i] + hpart[i] - stats[c]) * stats[C_ + c] * gamma[c] + beta[c] + xres[i];
        hbuf[i] = v > 0.f ? v : 0.f;
    }
}

extern "C" void kernel_launch(void* const* d_in, const int* in_sizes, int n_in,
                              void* d_out, int out_size, void* d_ws, size_t ws_size,
                              hipStream_t stream)
{
    const float* x      = (const float*)d_in[0];
    const float* w_off1 = (const float*)d_in[1];
    const float* b_off1 = (const float*)d_in[2];
    const float* w_dc1  = (const float*)d_in[3];
    const float* gamma1 = (const float*)d_in[4];
    const float* beta1  = (const float*)d_in[5];
    const float* w_off2 = (const float*)d_in[6];
    const float* b_off2 = (const float*)d_in[7];
    const float* w_dc2  = (const float*)d_in[8];
    const float* gamma2 = (const float*)d_in[9];
    const float* beta2  = (const float*)d_in[10];
    float* out = (float*)d_out;

    unsigned short* offb = (unsigned short*)d_ws;                    // 32,514,048
    unsigned short* xpad = offb + (size_t)B_ * OFFC_ * DHW_;         //  4,305,920
    unsigned short* h1pd = xpad + (size_t)B_ * G_ * PGSZ;            //  4,305,920
    unsigned short* wT2  = h1pd + (size_t)B_ * G_ * PGSZ;            //  1,327,104
    unsigned short* wdcT = wT2  + (size_t)OFFC_ * 2048;              //    110,592
    float* h1raw = (float*)(wdcT + (size_t)C_ * 1728);               //  3,211,264 f32
    float* hpart = h1raw + (size_t)B_ * C_ * DHW_;                   //  3,211,264 f32
    float* stats = hpart + (size_t)B_ * C_ * DHW_;                   //  128 f32
    float* part  = stats + 128;                                      //  2048 f32

    dim3 cgrid(11, 7, B_ * D_);
    dim3 dgrid(196, 32);
    dim3 sgrid(C_, 16);

    prep_kernel             <<<PACKB + TG1 + TG2, 256, 0, stream>>>(x, xpad, PACKB, w_off1, wT2, w_dc1, wdcT);
    conv_off_mfma_kernel    <<<cgrid, 512, 0, stream>>>(xpad, wT2, b_off1, offb);
    deform_mfma_kernel      <<<dgrid, 256, 0, stream>>>(xpad, offb, wdcT, h1raw, hpart);
    bn_stats_partial_kernel <<<sgrid, 256, 0, stream>>>(h1raw, hpart, part);
    bn_stats_finalize_kernel<<<1, 64, 0, stream>>>(part, stats);
    bn_relu_pack_kernel     <<<PACKB, 256, 0, stream>>>(h1raw, hpart, stats, gamma1, beta1, h1pd);

    prep_kernel             <<<TG1 + TG2, 256, 0, stream>>>(nullptr, nullptr, 0, w_off2, wT2, w_dc2, wdcT);
    conv_off_mfma_kernel    <<<cgrid, 512, 0, stream>>>(h1pd, wT2, b_off2, offb);
    deform_mfma_kernel      <<<dgrid, 256, 0, stream>>>(h1pd, offb, wdcT, out, hpart);
    bn_stats_partial_kernel <<<sgrid, 256, 0, stream>>>(out, hpart, part);
    bn_stats_finalize_kernel<<<1, 64, 0, stream>>>(part, stats);
    bn_add_relu_kernel      <<<1024, 256, 0, stream>>>(out, hpart, x, stats, gamma2, beta2);
}